// Round 2
// baseline (339.928 us; speedup 1.0000x reference)
//
#include <hip/hip_runtime.h>

// VectorQuantizer on MI355X — R10.
// R9 post-mortem: occupancy 39% (goal met) but MfmaUtil only 35% -> not latency
// but B-BANDWIDTH bound: 16 waves/CU x 8KB/slot = 128KB L2 ingress per CU-slot
// (2x duplicated across rw pairs) vs ~56 B/cyc/CU L2 share = ~2340cy of a 3337cy
// slot. R10: (1) score stages B via global_load_lds into double-buffered LDS
// (32KB/slot staged ONCE per block; dedup + async under compute; per-wave fetch
// moves to LDS pipe). Astage aliases Bbuf[0] -> 70KB LDS, 2 blocks/CU, 4 waves/
// SIMD kept. One barrier/slot (compiler vmcnt(0) drain is cheap: L2-resident src,
// ~1200cy compute phase to cover it). (2) packsetup grid 256->1024 (was 1 block/
// CU with serial stride-8 loads, ~30-40us hidden cost).

#define D        256
#define KCODES   8192
#define NROWS    32768
#define MB       64       // rows per block (score)
#define SLOTS    128      // chunk-slots (512 chunks / 4 code-quarters)
#define THREADS  512
#define CAP      32
#define MARGIN   0.03f    // f16 score err bound ~7e-3
#define BIAS     32.0f    // scores shifted positive so int-compare == float-compare
#define NOUT     8388608

typedef _Float16 h8_t __attribute__((ext_vector_type(8)));
typedef float    f4_t __attribute__((ext_vector_type(4)));

__device__ __forceinline__ float clipf(float v) { return fminf(1.0f, fmaxf(-1.0f, v)); }

__device__ __forceinline__ void gload_lds16(const void* g, void* l) {
  __builtin_amdgcn_global_load_lds(
      (const __attribute__((address_space(1))) unsigned int*)g,
      (__attribute__((address_space(3))) unsigned int*)l, 16, 0, 0);
}

#define DPP_ROR(x, n) __int_as_float(__builtin_amdgcn_update_dpp( \
    0, __float_as_int(x), 0x120 + (n), 0xF, 0xF, true))
__device__ __forceinline__ float maxrow16(float x) {
  x = fmaxf(x, DPP_ROR(x, 1));
  x = fmaxf(x, DPP_ROR(x, 2));
  x = fmaxf(x, DPP_ROR(x, 4));
  x = fmaxf(x, DPP_ROR(x, 8));
  return x;
}

// ---- pack f16 codebook, chunk-major fragment order + numpy-order sum(e^2) ----
__global__ void vq_packsetup(const float* __restrict__ emb, _Float16* __restrict__ femb,
                             float* __restrict__ senp, float* __restrict__ ekkb,
                             float* __restrict__ lossacc) {
  const int t = blockIdx.x;   // 1024 blocks
  if (t == 0 && threadIdx.x == 0) lossacc[0] = 0.0f;
  {
    int g = t * 256 + threadIdx.x;   // one global 16B unit per thread (262144)
    int ch = g >> 9, u = g & 511;
    int kc = u >> 6, ln = u & 63;
    int code = ch * 16 + (ln & 15);
    int k0 = kc * 32 + (ln >> 4) * 8;
    const float* sp = emb + (size_t)code * D + k0;
    f4_t v0 = *(const f4_t*)sp, v1 = *(const f4_t*)(sp + 4);
    h8_t h;
    h[0] = (_Float16)v0[0]; h[1] = (_Float16)v0[1];
    h[2] = (_Float16)v0[2]; h[3] = (_Float16)v0[3];
    h[4] = (_Float16)v1[0]; h[5] = (_Float16)v1[1];
    h[6] = (_Float16)v1[2]; h[7] = (_Float16)v1[3];
    *(h8_t*)(femb + (size_t)g * 8) = h;
  }
  if (t < 256) {   // senp/ekkb: byte-identical computation to previous rounds
    const int lane = threadIdx.x & 63;
    const int w    = threadIdx.x >> 6;
    const int jdx  = lane & 15, hf = jdx >> 3, jj = jdx & 7;
    #pragma unroll
    for (int cc = 0; cc < 2; ++cc) {
      int k = t * 32 + w * 8 + cc * 4 + (lane >> 4);
      const float* base = emb + (size_t)k * D + hf * 128 + jj;
      float v = base[0];
      float r = v * v;
      #pragma unroll
      for (int m = 1; m < 16; ++m) { v = base[8 * m]; r += v * v; }
      r += __shfl_xor(r, 1, 64);
      r += __shfl_xor(r, 2, 64);
      r += __shfl_xor(r, 4, 64);
      r += __shfl_xor(r, 8, 64);
      if (jdx == 0) { senp[k] = r; ekkb[k] = 0.5f * r - BIAS; }
    }
  }
}

// ---------------- score: LDS-staged B + MFMA + margin filter ----------------
__global__ void __launch_bounds__(THREADS, 4)
vq_score(const float* __restrict__ xin, const _Float16* __restrict__ femb,
         const float* __restrict__ ekkb, int* __restrict__ gcnt,
         unsigned short* __restrict__ gcand) {
  __shared__ alignas(16) char Bbuf[2][32768];  // double-buffered B (slot = 4 chunks)
  __shared__ int rowmaxI[MB];
  __shared__ int cnt[MB];
  __shared__ unsigned short cand[MB][CAP];     // total ~70 KB -> 2 blocks/CU

  const int tid  = threadIdx.x;
  const int lane = tid & 63;
  const int wid  = tid >> 6;     // 0..7
  const int l15  = lane & 15;
  const int quad = lane >> 4;
  const int rw   = wid >> 2;     // 0..1 : 32-row half
  const int cq   = wid & 3;      // 0..3 : code quarter
  const int r0   = blockIdx.x * MB;

  for (int i = tid; i < MB; i += THREADS) { rowmaxI[i] = 0; cnt[i] = 0; }

  // stage A (clip + f16, fragment order) into Bbuf[0] region (transient alias)
  {
    char* Astage = &Bbuf[0][0];
    #pragma unroll
    for (int j = 0; j < 4; ++j) {
      int c = j * THREADS + tid;          // 0..2047
      int ms = c >> 9, kc = (c >> 6) & 7, ln = c & 63;
      int row = ms * 16 + (ln & 15);
      int k0 = kc * 32 + (ln >> 4) * 8;
      const float* ap = xin + (size_t)(r0 + row) * D + k0;
      f4_t v0 = *(const f4_t*)ap, v1 = *(const f4_t*)(ap + 4);
      h8_t h;
      h[0] = (_Float16)clipf(v0[0]); h[1] = (_Float16)clipf(v0[1]);
      h[2] = (_Float16)clipf(v0[2]); h[3] = (_Float16)clipf(v0[3]);
      h[4] = (_Float16)clipf(v1[0]); h[5] = (_Float16)clipf(v1[1]);
      h[6] = (_Float16)clipf(v1[2]); h[7] = (_Float16)clipf(v1[3]);
      *(h8_t*)(Astage + (size_t)c * 16) = h;
    }
  }
  __syncthreads();

  // A fragments -> registers: 32 rows per wave (rw half), 64 VGPR
  h8_t afrag[2][8];
  #pragma unroll
  for (int m = 0; m < 2; ++m)
    #pragma unroll
    for (int kc = 0; kc < 8; ++kc)
      afrag[m][kc] = *(const h8_t*)(&Bbuf[0][0] +
          (size_t)(((rw * 2 + m) * 512 + kc * 64 + lane) * 16));
  __syncthreads();   // all afrag reads done; Bbuf[0] is free for B staging

  // prologue: stage slot 0 -> Bbuf[0] (32KB contiguous in femb, staged once/block)
  const char* fb = (const char*)femb;
  #pragma unroll
  for (int j = 0; j < 4; ++j) {
    int off = j * 8192 + wid * 1024 + lane * 16;
    gload_lds16(fb + off, &Bbuf[0][off]);
  }
  float ekcur = ekkb[cq * 16 + l15];
  float Gm[2];
  Gm[0] = -1e30f; Gm[1] = -1e30f;
  __syncthreads();   // vmcnt(0) drain before barrier -> Bbuf[0] ready

  for (int s = 0; s < SLOTS; ++s) {
    const int cur = s & 1;
    // async stage of next slot into the other buffer (in flight under compute)
    if (s + 1 < SLOTS) {
      #pragma unroll
      for (int j = 0; j < 4; ++j) {
        int off = j * 8192 + wid * 1024 + lane * 16;
        gload_lds16(fb + (size_t)(s + 1) * 32768 + off, &Bbuf[cur ^ 1][off]);
      }
    }
    const int sn = (s + 1 < SLOTS) ? s + 1 : s;
    float eknext = ekkb[(sn * 4 + cq) * 16 + l15];

    // B fragments for this wave's chunk from LDS
    h8_t bcur[8];
    #pragma unroll
    for (int kc = 0; kc < 8; ++kc)
      bcur[kc] = *(const h8_t*)(&Bbuf[cur][cq * 8192 + kc * 1024 + lane * 16]);

    f4_t acc[2];
    #pragma unroll
    for (int m = 0; m < 2; ++m) { f4_t z = {0.f, 0.f, 0.f, 0.f}; acc[m] = z; }
    #pragma unroll
    for (int kc = 0; kc < 8; ++kc)
      #pragma unroll
      for (int m = 0; m < 2; ++m)
        acc[m] = __builtin_amdgcn_mfma_f32_16x16x32_f16(afrag[m][kc], bcur[kc], acc[m], 0, 0, 0);

    const int ch = s * 4 + cq;
    #pragma unroll
    for (int m = 0; m < 2; ++m) {
      float ts[4];
      #pragma unroll
      for (int r = 0; r < 4; ++r) ts[r] = acc[m][r] - ekcur;
      float tmx = fmaxf(fmaxf(ts[0], ts[1]), fmaxf(ts[2], ts[3]));
      if (__any(tmx > Gm[m])) {
        float cmin = 1e30f;
        #pragma unroll
        for (int r = 0; r < 4; ++r) {
          int row_ = rw * 32 + m * 16 + quad * 4 + r;
          float mm = maxrow16(ts[r]);
          if (l15 == 0) atomicMax(&rowmaxI[row_], __float_as_int(mm));
          float cut = __int_as_float(rowmaxI[row_]) - MARGIN;
          cmin = fminf(cmin, cut);
          if (ts[r] >= cut) {
            int sidx = atomicAdd(&cnt[row_], 1);
            if (sidx < CAP) cand[row_][sidx] = (unsigned short)(ch * 16 + l15);
          }
        }
        Gm[m] = cmin;
      }
    }
    ekcur = eknext;
    __syncthreads();   // drains stage (vmcnt0) + all reads of Bbuf[cur] done
  }

  // dump candidates to global
  for (int i = tid; i < MB; i += THREADS) {
    int c = cnt[i];
    gcnt[r0 + i] = c > CAP ? CAP : c;
  }
  const unsigned int* cu = (const unsigned int*)cand;
  unsigned int* gu = (unsigned int*)gcand + (size_t)r0 * (CAP / 2);
  for (int i = tid; i < MB * (CAP / 2); i += THREADS) gu[i] = cu[i];
}

// ---------------- exact rescore: 8 lanes per candidate, butterfly argmin ----------------
__global__ void __launch_bounds__(512)
vq_rescore(const float* __restrict__ xin, const float* __restrict__ emb,
           const float* __restrict__ senp, const int* __restrict__ gcnt,
           const unsigned short* __restrict__ gcand, float* __restrict__ out,
           float* __restrict__ lossacc) {
  __shared__ float xrow[8][D];
  __shared__ float rpart[8][16];
  __shared__ float blksum;
  const int tid  = threadIdx.x;
  const int lane = tid & 63;
  const int wid  = tid >> 6;     // 0..7
  const int g    = lane >> 3;    // candidate slot within batch (0..7)
  const int e    = lane & 7;     // 32-elem octant (0..7)
  const int r0   = blockIdx.x * 64;
  if (tid == 0) blksum = 0.0f;
  __syncthreads();

  const int lane4 = lane * 4;
  for (int rr = 0; rr < 8; ++rr) {
    const int row = wid + rr * 8;
    f4_t xv = *(const f4_t*)(xin + (size_t)(r0 + row) * D + lane4);
    xv[0] = clipf(xv[0]); xv[1] = clipf(xv[1]); xv[2] = clipf(xv[2]); xv[3] = clipf(xv[3]);
    *(f4_t*)&xrow[wid][lane4] = xv;
    __builtin_amdgcn_wave_barrier();
    if (lane < 16) {   // numpy pairwise sum of x^2 (exact order)
      const int hf = lane >> 3, jj = lane & 7;
      const float* base = &xrow[wid][hf * 128 + jj];
      float v = base[0];
      float rs = v * v;
      #pragma unroll
      for (int m = 1; m < 16; ++m) { v = base[8 * m]; rs += v * v; }
      rpart[wid][lane] = rs;
    }
    __builtin_amdgcn_wave_barrier();
    float p[16];
    #pragma unroll
    for (int j = 0; j < 16; ++j) p[j] = rpart[wid][j];
    float h0 = ((p[0] + p[1]) + (p[2] + p[3])) + ((p[4] + p[5]) + (p[6] + p[7]));
    float h1 = ((p[8] + p[9]) + (p[10] + p[11])) + ((p[12] + p[13]) + (p[14] + p[15]));
    float sx = h0 + h1;

    // hoist this lane's x octant (32 floats)
    f4_t xo[8];
    #pragma unroll
    for (int u = 0; u < 8; ++u) xo[u] = *(const f4_t*)&xrow[wid][e * 32 + u * 4];

    const int nc = gcnt[r0 + row];
    const unsigned short* cl = gcand + (size_t)(r0 + row) * CAP;
    float bd = INFINITY; int bk = 0x7fffffff;
    for (int bi = 0; bi < (nc + 7) >> 3; ++bi) {
      int ci = bi * 8 + g;
      bool valid = ci < nc;
      int k = valid ? cl[ci] : 0;
      const float* ep = emb + (size_t)k * D + e * 32;
      double dd = 0.0;
      #pragma unroll
      for (int u = 0; u < 8; ++u) {
        f4_t ev = *(const f4_t*)(ep + u * 4);
        dd += (double)xo[u][0] * (double)ev[0] + (double)xo[u][1] * (double)ev[1]
            + (double)xo[u][2] * (double)ev[2] + (double)xo[u][3] * (double)ev[3];
      }
      dd += __shfl_xor(dd, 1, 64);
      dd += __shfl_xor(dd, 2, 64);
      dd += __shfl_xor(dd, 4, 64);   // all 8 lanes of the group hold the full dot
      float T1 = sx + senp[k];       // fp32, numpy op order
      float T2 = (float)(2.0 * dd);
      float d  = valid ? (T1 - T2) : INFINITY;
      int   kk = valid ? k : 0x7fffffff;
      if (d < bd || (d == bd && kk < bk)) { bd = d; bk = kk; }
    }
    // cross-group lexicographic argmin (associative & commutative -> exact)
    #pragma unroll
    for (int off = 8; off < 64; off <<= 1) {
      float od = __shfl_xor(bd, off, 64);
      int   ok = __shfl_xor(bk, off, 64);
      if (od < bd || (od == bd && ok < bk)) { bd = od; bk = ok; }
    }

    f4_t ev = *(const f4_t*)(emb + (size_t)bk * D + lane4);
    *(f4_t*)(out + (size_t)(r0 + row) * D + lane4) = ev;
    float ls = 0.0f;
    #pragma unroll
    for (int i = 0; i < 4; ++i) { float df = ev[i] - xv[i]; ls += df * df; }
    #pragma unroll
    for (int off = 1; off < 64; off <<= 1) ls += __shfl_xor(ls, off, 64);
    if (lane == 0) atomicAdd(&blksum, ls);
  }
  __syncthreads();
  if (tid == 0) atomicAdd(lossacc, blksum);
}

// ---------------- finalize loss ----------------
__global__ void vq_fin(const float* __restrict__ lossacc, float* __restrict__ out) {
  out[NOUT] = 1.25f * lossacc[0] / 8388608.0f;
}

extern "C" void kernel_launch(void* const* d_in, const int* in_sizes, int n_in,
                              void* d_out, int out_size, void* d_ws, size_t ws_size,
                              hipStream_t stream) {
  const float* xin = (const float*)d_in[0];
  const float* emb = (const float*)d_in[1];
  float* out = (float*)d_out;
  _Float16* femb = (_Float16*)d_ws;                 // 4 MB (512 chunks x 8 KB)
  float* F       = (float*)d_ws + 1048576;
  float* senp    = F;                               // 8192
  float* ekkb    = F + 8192;                        // 8192
  float* lossacc = F + 16384;                       // 1
  int*   gcnt    = (int*)(F + 16640);               // 32768 ints
  unsigned short* gcand = (unsigned short*)(F + 16640 + 32768);  // 32768*32 u16
  vq_packsetup<<<dim3(1024), dim3(256), 0, stream>>>(emb, femb, senp, ekkb, lossacc);
  vq_score<<<dim3(NROWS / MB), dim3(THREADS), 0, stream>>>(xin, femb, ekkb, gcnt, gcand);
  vq_rescore<<<dim3(NROWS / 64), dim3(512), 0, stream>>>(xin, emb, senp, gcnt, gcand, out, lossacc);
  vq_fin<<<dim3(1), dim3(1), 0, stream>>>(lossacc, out);
}

// Round 3
// 321.333 us; speedup vs baseline: 1.0579x; 1.0579x over previous
//
#include <hip/hip_runtime.h>

// VectorQuantizer on MI355X — R11.
// R10 post-mortem: LDS-staged B regressed (236us, MfmaUtil 25.6%): 192KB/CU-slot
// LDS port traffic (write+read round trip) ~= 4100cy/slot vs R9's direct L2->reg
// 2286cy. LDS is only 1.7x the L2 port here -> round-trip + per-slot barrier
// lockstep is a net loss. R11: (1) vq_score reverted verbatim to R9 (178us,
// 772 TF effective); (2) packsetup stays grid-1024; (3) rescore restructured:
// rows with nc==1 are PROVEN decided by the margin invariant (true argmin always
// in the list; singleton => f16 argmax == exact argmin) -> fast path = batched
// emb gather + out write + deferred per-wave loss reduce, no sx/dots/butterflies.
// Full exact path only for nc>=2 rows.

#define D        256
#define KCODES   8192
#define NROWS    32768
#define MB       64       // rows per block (score)
#define SLOTS    128      // chunk-slots per wave (512 chunks / 4 code-quarters)
#define THREADS  512
#define CAP      32
#define MARGIN   0.03f    // f16 score err bound ~7e-3
#define BIAS     32.0f    // scores shifted positive so int-compare == float-compare
#define NOUT     8388608

typedef _Float16 h8_t __attribute__((ext_vector_type(8)));
typedef float    f4_t __attribute__((ext_vector_type(4)));

__device__ __forceinline__ float clipf(float v) { return fminf(1.0f, fmaxf(-1.0f, v)); }

#define DPP_ROR(x, n) __int_as_float(__builtin_amdgcn_update_dpp( \
    0, __float_as_int(x), 0x120 + (n), 0xF, 0xF, true))
__device__ __forceinline__ float maxrow16(float x) {
  x = fmaxf(x, DPP_ROR(x, 1));
  x = fmaxf(x, DPP_ROR(x, 2));
  x = fmaxf(x, DPP_ROR(x, 4));
  x = fmaxf(x, DPP_ROR(x, 8));
  return x;
}

// ---- pack f16 codebook, chunk-major fragment order + numpy-order sum(e^2) ----
__global__ void vq_packsetup(const float* __restrict__ emb, _Float16* __restrict__ femb,
                             float* __restrict__ senp, float* __restrict__ ekkb,
                             float* __restrict__ lossacc) {
  const int t = blockIdx.x;   // 1024 blocks
  if (t == 0 && threadIdx.x == 0) lossacc[0] = 0.0f;
  {
    int g = t * 256 + threadIdx.x;   // one global 16B unit per thread (262144)
    int ch = g >> 9, u = g & 511;
    int kc = u >> 6, ln = u & 63;
    int code = ch * 16 + (ln & 15);
    int k0 = kc * 32 + (ln >> 4) * 8;
    const float* sp = emb + (size_t)code * D + k0;
    f4_t v0 = *(const f4_t*)sp, v1 = *(const f4_t*)(sp + 4);
    h8_t h;
    h[0] = (_Float16)v0[0]; h[1] = (_Float16)v0[1];
    h[2] = (_Float16)v0[2]; h[3] = (_Float16)v0[3];
    h[4] = (_Float16)v1[0]; h[5] = (_Float16)v1[1];
    h[6] = (_Float16)v1[2]; h[7] = (_Float16)v1[3];
    *(h8_t*)(femb + (size_t)g * 8) = h;
  }
  if (t < 256) {   // senp/ekkb: byte-identical computation to previous rounds
    const int lane = threadIdx.x & 63;
    const int w    = threadIdx.x >> 6;
    const int jdx  = lane & 15, hf = jdx >> 3, jj = jdx & 7;
    #pragma unroll
    for (int cc = 0; cc < 2; ++cc) {
      int k = t * 32 + w * 8 + cc * 4 + (lane >> 4);
      const float* base = emb + (size_t)k * D + hf * 128 + jj;
      float v = base[0];
      float r = v * v;
      #pragma unroll
      for (int m = 1; m < 16; ++m) { v = base[8 * m]; r += v * v; }
      r += __shfl_xor(r, 1, 64);
      r += __shfl_xor(r, 2, 64);
      r += __shfl_xor(r, 4, 64);
      r += __shfl_xor(r, 8, 64);
      if (jdx == 0) { senp[k] = r; ekkb[k] = 0.5f * r - BIAS; }
    }
  }
}

// ---------------- score: MFMA + margin filter -> global candidate lists ----------------
// (verbatim R9 structure: direct L2->reg B stream, 4 waves/SIMD, 178us measured)
__global__ void __launch_bounds__(THREADS, 4)
vq_score(const float* __restrict__ xin, const _Float16* __restrict__ femb,
         const float* __restrict__ ekkb, int* __restrict__ gcnt,
         unsigned short* __restrict__ gcand) {
  __shared__ alignas(16) char Astage[32768];   // 64 rows x 256 k f16, fragment order
  __shared__ int rowmaxI[MB];
  __shared__ int cnt[MB];
  __shared__ unsigned short cand[MB][CAP];     // 4 KB; total ~37.5 KB -> 2 blocks/CU

  const int tid  = threadIdx.x;
  const int lane = tid & 63;
  const int wid  = tid >> 6;     // 0..7
  const int l15  = lane & 15;
  const int quad = lane >> 4;
  const int rw   = wid >> 2;     // 0..1 : 32-row half
  const int cq   = wid & 3;      // 0..3 : code quarter
  const int r0   = blockIdx.x * MB;

  for (int i = tid; i < MB; i += THREADS) { rowmaxI[i] = 0; cnt[i] = 0; }

  // stage A (clip + f16, chunk-major fragment order: 64 rows x 256 k = 2048 units)
  #pragma unroll
  for (int j = 0; j < 4; ++j) {
    int c = j * THREADS + tid;          // 0..2047
    int ms = c >> 9, kc = (c >> 6) & 7, ln = c & 63;
    int row = ms * 16 + (ln & 15);
    int k0 = kc * 32 + (ln >> 4) * 8;
    const float* ap = xin + (size_t)(r0 + row) * D + k0;
    f4_t v0 = *(const f4_t*)ap, v1 = *(const f4_t*)(ap + 4);
    h8_t h;
    h[0] = (_Float16)clipf(v0[0]); h[1] = (_Float16)clipf(v0[1]);
    h[2] = (_Float16)clipf(v0[2]); h[3] = (_Float16)clipf(v0[3]);
    h[4] = (_Float16)clipf(v1[0]); h[5] = (_Float16)clipf(v1[1]);
    h[6] = (_Float16)clipf(v1[2]); h[7] = (_Float16)clipf(v1[3]);
    *(h8_t*)(Astage + (size_t)c * 16) = h;
  }
  __syncthreads();

  // A fragments -> registers: 32 rows per wave (rw half), 64 VGPR
  h8_t afrag[2][8];
  #pragma unroll
  for (int m = 0; m < 2; ++m)
    #pragma unroll
    for (int kc = 0; kc < 8; ++kc)
      afrag[m][kc] = *(const h8_t*)(Astage +
          (size_t)(((rw * 2 + m) * 512 + kc * 64 + lane) * 16));

  float Gm[2];
  Gm[0] = -1e30f; Gm[1] = -1e30f;

  // ---- K-loop: single B buffer; MFMA consumes bcur, then next-slot loads
  // immediately re-target bcur (in-flight across the epilogue; vmcnt satisfied
  // right before the next iteration's first MFMA). 4 waves/SIMD hide the rest.
  h8_t bcur[8]; float ekcur;
  {
    const _Float16* bb = femb + (size_t)cq * 4096 + lane * 8;
    #pragma unroll
    for (int kc = 0; kc < 8; ++kc) bcur[kc] = *(const h8_t*)(bb + kc * 512);
    ekcur = ekkb[cq * 16 + l15];
  }

  for (int s = 0; s < SLOTS; ++s) {
    f4_t acc[2];
    #pragma unroll
    for (int m = 0; m < 2; ++m) { f4_t z = {0.f, 0.f, 0.f, 0.f}; acc[m] = z; }
    #pragma unroll
    for (int kc = 0; kc < 8; ++kc)
      #pragma unroll
      for (int m = 0; m < 2; ++m)
        acc[m] = __builtin_amdgcn_mfma_f32_16x16x32_f16(afrag[m][kc], bcur[kc], acc[m], 0, 0, 0);

    // issue next-slot loads now (overwrite bcur; epilogue sits in their shadow)
    const int sn = (s + 1 < SLOTS) ? s + 1 : s;   // clamped prefetch (always in-bounds)
    float eknext;
    {
      const _Float16* bb = femb + (size_t)(sn * 4 + cq) * 4096 + lane * 8;
      #pragma unroll
      for (int kc = 0; kc < 8; ++kc) bcur[kc] = *(const h8_t*)(bb + kc * 512);
      eknext = ekkb[(sn * 4 + cq) * 16 + l15];
    }

    const int ch = s * 4 + cq;
    #pragma unroll
    for (int m = 0; m < 2; ++m) {
      float ts[4];
      #pragma unroll
      for (int r = 0; r < 4; ++r) ts[r] = acc[m][r] - ekcur;
      float tmx = fmaxf(fmaxf(ts[0], ts[1]), fmaxf(ts[2], ts[3]));
      if (__any(tmx > Gm[m])) {
        float cmin = 1e30f;
        #pragma unroll
        for (int r = 0; r < 4; ++r) {
          int row_ = rw * 32 + m * 16 + quad * 4 + r;
          float mm = maxrow16(ts[r]);
          if (l15 == 0) atomicMax(&rowmaxI[row_], __float_as_int(mm));
          float cut = __int_as_float(rowmaxI[row_]) - MARGIN;
          cmin = fminf(cmin, cut);
          if (ts[r] >= cut) {
            int sidx = atomicAdd(&cnt[row_], 1);
            if (sidx < CAP) cand[row_][sidx] = (unsigned short)(ch * 16 + l15);
          }
        }
        Gm[m] = cmin;
      }
    }
    ekcur = eknext;
    if ((s & 31) == 31) __syncthreads();   // keep waves in the same L2 window
  }
  __syncthreads();

  // dump candidates to global
  for (int i = tid; i < MB; i += THREADS) {
    int c = cnt[i];
    gcnt[r0 + i] = c > CAP ? CAP : c;
  }
  const unsigned int* cu = (const unsigned int*)cand;
  unsigned int* gu = (unsigned int*)gcand + (size_t)r0 * (CAP / 2);
  for (int i = tid; i < MB * (CAP / 2); i += THREADS) gu[i] = cu[i];
}

// ---------------- rescore: nc==1 fast path + exact slow path ----------------
// Margin invariant: the exact argmin is ALWAYS in the candidate list (its f16
// score is >= rowmax - 2*err >= rowmax - MARGIN). nc==1 => that sole candidate
// IS the exact argmin; no distances needed, just gather + loss.
__global__ void __launch_bounds__(512)
vq_rescore(const float* __restrict__ xin, const float* __restrict__ emb,
           const float* __restrict__ senp, const int* __restrict__ gcnt,
           const unsigned short* __restrict__ gcand, float* __restrict__ out,
           float* __restrict__ lossacc) {
  __shared__ float xrow[8][D];
  __shared__ float rpart[8][16];
  __shared__ float blksum;
  const int tid  = threadIdx.x;
  const int lane = tid & 63;
  const int wid  = tid >> 6;     // 0..7
  const int g    = lane >> 3;    // candidate slot within batch (0..7)
  const int e    = lane & 7;     // 32-elem octant (0..7)
  const int r0   = blockIdx.x * 64;
  if (tid == 0) blksum = 0.0f;
  __syncthreads();

  const int lane4 = lane * 4;
  float lacc = 0.0f;             // per-lane loss accumulator (deferred reduce)

  // classify this wave's 8 rows (row = wid + rr*8)
  int ncs[8], k0s[8];
  #pragma unroll
  for (int rr = 0; rr < 8; ++rr) {
    int row = r0 + wid + rr * 8;
    ncs[rr] = gcnt[row];
    k0s[rr] = gcand[(size_t)row * CAP];
  }

  // ---- fast rows: batched independent loads (one latency window) ----
  f4_t evs[8], xvs[8];
  #pragma unroll
  for (int rr = 0; rr < 8; ++rr) {
    if (ncs[rr] == 1) {          // wave-uniform branch
      int row = r0 + wid + rr * 8;
      xvs[rr] = *(const f4_t*)(xin + (size_t)row * D + lane4);
      evs[rr] = *(const f4_t*)(emb + (size_t)k0s[rr] * D + lane4);
    }
  }
  #pragma unroll
  for (int rr = 0; rr < 8; ++rr) {
    if (ncs[rr] == 1) {
      int row = r0 + wid + rr * 8;
      f4_t xv = xvs[rr];
      xv[0] = clipf(xv[0]); xv[1] = clipf(xv[1]);
      xv[2] = clipf(xv[2]); xv[3] = clipf(xv[3]);
      f4_t ev = evs[rr];
      *(f4_t*)(out + (size_t)row * D + lane4) = ev;
      #pragma unroll
      for (int i = 0; i < 4; ++i) { float df = ev[i] - xv[i]; lacc += df * df; }
    }
  }

  // ---- slow rows: full exact rescore (unchanged semantics) ----
  for (int rr = 0; rr < 8; ++rr) {
    if (ncs[rr] != 1) {          // wave-uniform
      const int row = wid + rr * 8;
      f4_t xv = *(const f4_t*)(xin + (size_t)(r0 + row) * D + lane4);
      xv[0] = clipf(xv[0]); xv[1] = clipf(xv[1]);
      xv[2] = clipf(xv[2]); xv[3] = clipf(xv[3]);
      *(f4_t*)&xrow[wid][lane4] = xv;
      __builtin_amdgcn_wave_barrier();
      if (lane < 16) {   // numpy pairwise sum of x^2 (exact order)
        const int hf = lane >> 3, jj = lane & 7;
        const float* base = &xrow[wid][hf * 128 + jj];
        float v = base[0];
        float rs = v * v;
        #pragma unroll
        for (int m = 1; m < 16; ++m) { v = base[8 * m]; rs += v * v; }
        rpart[wid][lane] = rs;
      }
      __builtin_amdgcn_wave_barrier();
      float p[16];
      #pragma unroll
      for (int j = 0; j < 16; ++j) p[j] = rpart[wid][j];
      float h0 = ((p[0] + p[1]) + (p[2] + p[3])) + ((p[4] + p[5]) + (p[6] + p[7]));
      float h1 = ((p[8] + p[9]) + (p[10] + p[11])) + ((p[12] + p[13]) + (p[14] + p[15]));
      float sx = h0 + h1;

      // hoist this lane's x octant (32 floats)
      f4_t xo[8];
      #pragma unroll
      for (int u = 0; u < 8; ++u) xo[u] = *(const f4_t*)&xrow[wid][e * 32 + u * 4];

      const int nc = ncs[rr];
      const unsigned short* cl = gcand + (size_t)(r0 + row) * CAP;
      float bd = INFINITY; int bk = 0x7fffffff;
      for (int bi = 0; bi < (nc + 7) >> 3; ++bi) {
        int ci = bi * 8 + g;
        bool valid = ci < nc;
        int k = valid ? cl[ci] : 0;
        const float* ep = emb + (size_t)k * D + e * 32;
        double dd = 0.0;
        #pragma unroll
        for (int u = 0; u < 8; ++u) {
          f4_t ev = *(const f4_t*)(ep + u * 4);
          dd += (double)xo[u][0] * (double)ev[0] + (double)xo[u][1] * (double)ev[1]
              + (double)xo[u][2] * (double)ev[2] + (double)xo[u][3] * (double)ev[3];
        }
        dd += __shfl_xor(dd, 1, 64);
        dd += __shfl_xor(dd, 2, 64);
        dd += __shfl_xor(dd, 4, 64);   // all 8 lanes of the group hold the full dot
        float T1 = sx + senp[k];       // fp32, numpy op order
        float T2 = (float)(2.0 * dd);
        float d  = valid ? (T1 - T2) : INFINITY;
        int   kk = valid ? k : 0x7fffffff;
        if (d < bd || (d == bd && kk < bk)) { bd = d; bk = kk; }
      }
      // cross-group lexicographic argmin (associative & commutative -> exact)
      #pragma unroll
      for (int off = 8; off < 64; off <<= 1) {
        float od = __shfl_xor(bd, off, 64);
        int   ok = __shfl_xor(bk, off, 64);
        if (od < bd || (od == bd && ok < bk)) { bd = od; bk = ok; }
      }

      f4_t ev = *(const f4_t*)(emb + (size_t)bk * D + lane4);
      *(f4_t*)(out + (size_t)(r0 + row) * D + lane4) = ev;
      #pragma unroll
      for (int i = 0; i < 4; ++i) { float df = ev[i] - xv[i]; lacc += df * df; }
    }
  }

  // one reduce per wave, one LDS atomic per wave, one global atomic per block
  #pragma unroll
  for (int off = 1; off < 64; off <<= 1) lacc += __shfl_xor(lacc, off, 64);
  if (lane == 0) atomicAdd(&blksum, lacc);
  __syncthreads();
  if (tid == 0) atomicAdd(lossacc, blksum);
}

// ---------------- finalize loss ----------------
__global__ void vq_fin(const float* __restrict__ lossacc, float* __restrict__ out) {
  out[NOUT] = 1.25f * lossacc[0] / 8388608.0f;
}

extern "C" void kernel_launch(void* const* d_in, const int* in_sizes, int n_in,
                              void* d_out, int out_size, void* d_ws, size_t ws_size,
                              hipStream_t stream) {
  const float* xin = (const float*)d_in[0];
  const float* emb = (const float*)d_in[1];
  float* out = (float*)d_out;
  _Float16* femb = (_Float16*)d_ws;                 // 4 MB (512 chunks x 8 KB)
  float* F       = (float*)d_ws + 1048576;
  float* senp    = F;                               // 8192
  float* ekkb    = F + 8192;                        // 8192
  float* lossacc = F + 16384;                       // 1
  int*   gcnt    = (int*)(F + 16640);               // 32768 ints
  unsigned short* gcand = (unsigned short*)(F + 16640 + 32768);  // 32768*32 u16
  vq_packsetup<<<dim3(1024), dim3(256), 0, stream>>>(emb, femb, senp, ekkb, lossacc);
  vq_score<<<dim3(NROWS / MB), dim3(THREADS), 0, stream>>>(xin, femb, ekkb, gcnt, gcand);
  vq_rescore<<<dim3(NROWS / 64), dim3(512), 0, stream>>>(xin, emb, senp, gcnt, gcand, out, lossacc);
  vq_fin<<<dim3(1), dim3(1), 0, stream>>>(lossacc, out);
}

// Round 4
// 279.791 us; speedup vs baseline: 1.2149x; 1.1485x over previous
//
#include <hip/hip_runtime.h>

// VectorQuantizer on MI355X — R12.
// R11 post-mortem: nc==1 fast path never fired — candidate lists are built vs
// the RUNNING max, so stale early entries keep cnt ~10-20. R12: vq_score
// epilogue COMPACTS each row's list against the FINAL rowmax (scores kept in
// LDS scoref[MB][CAP]); only entries within MARGIN of the final max survive.
// Invariant preserved (insertion cut <= final cut; final-max entry survives =>
// nc>=1; true argmin always within MARGIN of final f16 max => survives).
// Post-compaction nc==1 expected for ~85-90% of rows (top-2 gap ~0.22 >> 0.03)
// -> rescore fast path (gather+loss only) dominates. Score K-loop unchanged
// (R9 structure, 180us, L2-BW bound at 128KB/CU-slot; MFMA pipe 37% as counted:
// 64 MFMA/SIMD-slot x 19.4cy = 1242cy of 3375cy slot).

#define D        256
#define KCODES   8192
#define NROWS    32768
#define MB       64       // rows per block (score)
#define SLOTS    128      // chunk-slots per wave (512 chunks / 4 code-quarters)
#define THREADS  512
#define CAP      32
#define MARGIN   0.03f    // f16 score err bound ~7e-3
#define BIAS     32.0f    // scores shifted positive so int-compare == float-compare
#define NOUT     8388608

typedef _Float16 h8_t __attribute__((ext_vector_type(8)));
typedef float    f4_t __attribute__((ext_vector_type(4)));

__device__ __forceinline__ float clipf(float v) { return fminf(1.0f, fmaxf(-1.0f, v)); }

#define DPP_ROR(x, n) __int_as_float(__builtin_amdgcn_update_dpp( \
    0, __float_as_int(x), 0x120 + (n), 0xF, 0xF, true))
__device__ __forceinline__ float maxrow16(float x) {
  x = fmaxf(x, DPP_ROR(x, 1));
  x = fmaxf(x, DPP_ROR(x, 2));
  x = fmaxf(x, DPP_ROR(x, 4));
  x = fmaxf(x, DPP_ROR(x, 8));
  return x;
}

// ---- pack f16 codebook, chunk-major fragment order + numpy-order sum(e^2) ----
__global__ void vq_packsetup(const float* __restrict__ emb, _Float16* __restrict__ femb,
                             float* __restrict__ senp, float* __restrict__ ekkb,
                             float* __restrict__ lossacc) {
  const int t = blockIdx.x;   // 1024 blocks
  if (t == 0 && threadIdx.x == 0) lossacc[0] = 0.0f;
  {
    int g = t * 256 + threadIdx.x;   // one global 16B unit per thread (262144)
    int ch = g >> 9, u = g & 511;
    int kc = u >> 6, ln = u & 63;
    int code = ch * 16 + (ln & 15);
    int k0 = kc * 32 + (ln >> 4) * 8;
    const float* sp = emb + (size_t)code * D + k0;
    f4_t v0 = *(const f4_t*)sp, v1 = *(const f4_t*)(sp + 4);
    h8_t h;
    h[0] = (_Float16)v0[0]; h[1] = (_Float16)v0[1];
    h[2] = (_Float16)v0[2]; h[3] = (_Float16)v0[3];
    h[4] = (_Float16)v1[0]; h[5] = (_Float16)v1[1];
    h[6] = (_Float16)v1[2]; h[7] = (_Float16)v1[3];
    *(h8_t*)(femb + (size_t)g * 8) = h;
  }
  if (t < 256) {   // senp/ekkb: byte-identical computation to previous rounds
    const int lane = threadIdx.x & 63;
    const int w    = threadIdx.x >> 6;
    const int jdx  = lane & 15, hf = jdx >> 3, jj = jdx & 7;
    #pragma unroll
    for (int cc = 0; cc < 2; ++cc) {
      int k = t * 32 + w * 8 + cc * 4 + (lane >> 4);
      const float* base = emb + (size_t)k * D + hf * 128 + jj;
      float v = base[0];
      float r = v * v;
      #pragma unroll
      for (int m = 1; m < 16; ++m) { v = base[8 * m]; r += v * v; }
      r += __shfl_xor(r, 1, 64);
      r += __shfl_xor(r, 2, 64);
      r += __shfl_xor(r, 4, 64);
      r += __shfl_xor(r, 8, 64);
      if (jdx == 0) { senp[k] = r; ekkb[k] = 0.5f * r - BIAS; }
    }
  }
}

// ---------------- score: MFMA + margin filter -> COMPACTED candidate lists ----------------
__global__ void __launch_bounds__(THREADS, 4)
vq_score(const float* __restrict__ xin, const _Float16* __restrict__ femb,
         const float* __restrict__ ekkb, int* __restrict__ gcnt,
         unsigned short* __restrict__ gcand) {
  __shared__ alignas(16) char Astage[32768];   // 64 rows x 256 k f16, fragment order
  __shared__ int rowmaxI[MB];
  __shared__ int cnt[MB];
  __shared__ int ncnt[MB];
  __shared__ unsigned short cand[MB][CAP];     // 4 KB
  __shared__ float scoref[MB][CAP];            // 8 KB; total ~46 KB -> 2 blocks/CU

  const int tid  = threadIdx.x;
  const int lane = tid & 63;
  const int wid  = tid >> 6;     // 0..7
  const int l15  = lane & 15;
  const int quad = lane >> 4;
  const int rw   = wid >> 2;     // 0..1 : 32-row half
  const int cq   = wid & 3;      // 0..3 : code quarter
  const int r0   = blockIdx.x * MB;

  for (int i = tid; i < MB; i += THREADS) { rowmaxI[i] = 0; cnt[i] = 0; ncnt[i] = 0; }

  // stage A (clip + f16, chunk-major fragment order: 64 rows x 256 k = 2048 units)
  #pragma unroll
  for (int j = 0; j < 4; ++j) {
    int c = j * THREADS + tid;          // 0..2047
    int ms = c >> 9, kc = (c >> 6) & 7, ln = c & 63;
    int row = ms * 16 + (ln & 15);
    int k0 = kc * 32 + (ln >> 4) * 8;
    const float* ap = xin + (size_t)(r0 + row) * D + k0;
    f4_t v0 = *(const f4_t*)ap, v1 = *(const f4_t*)(ap + 4);
    h8_t h;
    h[0] = (_Float16)clipf(v0[0]); h[1] = (_Float16)clipf(v0[1]);
    h[2] = (_Float16)clipf(v0[2]); h[3] = (_Float16)clipf(v0[3]);
    h[4] = (_Float16)clipf(v1[0]); h[5] = (_Float16)clipf(v1[1]);
    h[6] = (_Float16)clipf(v1[2]); h[7] = (_Float16)clipf(v1[3]);
    *(h8_t*)(Astage + (size_t)c * 16) = h;
  }
  __syncthreads();

  // A fragments -> registers: 32 rows per wave (rw half), 64 VGPR
  h8_t afrag[2][8];
  #pragma unroll
  for (int m = 0; m < 2; ++m)
    #pragma unroll
    for (int kc = 0; kc < 8; ++kc)
      afrag[m][kc] = *(const h8_t*)(Astage +
          (size_t)(((rw * 2 + m) * 512 + kc * 64 + lane) * 16));

  float Gm[2];
  Gm[0] = -1e30f; Gm[1] = -1e30f;

  // ---- K-loop: single B buffer; MFMA consumes bcur, then next-slot loads
  // immediately re-target bcur (in-flight across the epilogue; vmcnt satisfied
  // right before the next iteration's first MFMA). 4 waves/SIMD hide the rest.
  h8_t bcur[8]; float ekcur;
  {
    const _Float16* bb = femb + (size_t)cq * 4096 + lane * 8;
    #pragma unroll
    for (int kc = 0; kc < 8; ++kc) bcur[kc] = *(const h8_t*)(bb + kc * 512);
    ekcur = ekkb[cq * 16 + l15];
  }

  for (int s = 0; s < SLOTS; ++s) {
    f4_t acc[2];
    #pragma unroll
    for (int m = 0; m < 2; ++m) { f4_t z = {0.f, 0.f, 0.f, 0.f}; acc[m] = z; }
    #pragma unroll
    for (int kc = 0; kc < 8; ++kc)
      #pragma unroll
      for (int m = 0; m < 2; ++m)
        acc[m] = __builtin_amdgcn_mfma_f32_16x16x32_f16(afrag[m][kc], bcur[kc], acc[m], 0, 0, 0);

    // issue next-slot loads now (overwrite bcur; epilogue sits in their shadow)
    const int sn = (s + 1 < SLOTS) ? s + 1 : s;   // clamped prefetch (always in-bounds)
    float eknext;
    {
      const _Float16* bb = femb + (size_t)(sn * 4 + cq) * 4096 + lane * 8;
      #pragma unroll
      for (int kc = 0; kc < 8; ++kc) bcur[kc] = *(const h8_t*)(bb + kc * 512);
      eknext = ekkb[(sn * 4 + cq) * 16 + l15];
    }

    const int ch = s * 4 + cq;
    #pragma unroll
    for (int m = 0; m < 2; ++m) {
      float ts[4];
      #pragma unroll
      for (int r = 0; r < 4; ++r) ts[r] = acc[m][r] - ekcur;
      float tmx = fmaxf(fmaxf(ts[0], ts[1]), fmaxf(ts[2], ts[3]));
      if (__any(tmx > Gm[m])) {
        float cmin = 1e30f;
        #pragma unroll
        for (int r = 0; r < 4; ++r) {
          int row_ = rw * 32 + m * 16 + quad * 4 + r;
          float mm = maxrow16(ts[r]);
          if (l15 == 0) atomicMax(&rowmaxI[row_], __float_as_int(mm));
          float cut = __int_as_float(rowmaxI[row_]) - MARGIN;
          cmin = fminf(cmin, cut);
          if (ts[r] >= cut) {
            int sidx = atomicAdd(&cnt[row_], 1);
            if (sidx < CAP) {
              cand[row_][sidx]   = (unsigned short)(ch * 16 + l15);
              scoref[row_][sidx] = ts[r];
            }
          }
        }
        Gm[m] = cmin;
      }
    }
    ekcur = eknext;
    if ((s & 31) == 31) __syncthreads();   // keep waves in the same L2 window
  }
  __syncthreads();

  // ---- compact vs FINAL row max, write survivors straight to global ----
  {
    const int row = tid >> 3, j = tid & 7;       // 8 threads per row
    int valid = cnt[row]; if (valid > CAP) valid = CAP;
    const float cut = __int_as_float(rowmaxI[row]) - MARGIN;
    for (int jj = j; jj < valid; jj += 8) {
      if (scoref[row][jj] >= cut) {
        int ns = atomicAdd(&ncnt[row], 1);
        gcand[(size_t)(r0 + row) * CAP + ns] = cand[row][jj];
      }
    }
  }
  __syncthreads();
  if (tid < MB) gcnt[r0 + tid] = ncnt[tid];
}

// ---------------- rescore: nc==1 fast path + exact slow path ----------------
// Post-compaction, nc is the count of codes within MARGIN of the FINAL f16 max.
// nc==1 => that candidate IS the exact argmin (margin invariant) -> gather+loss.
__global__ void __launch_bounds__(512)
vq_rescore(const float* __restrict__ xin, const float* __restrict__ emb,
           const float* __restrict__ senp, const int* __restrict__ gcnt,
           const unsigned short* __restrict__ gcand, float* __restrict__ out,
           float* __restrict__ lossacc) {
  __shared__ float xrow[8][D];
  __shared__ float rpart[8][16];
  __shared__ float blksum;
  const int tid  = threadIdx.x;
  const int lane = tid & 63;
  const int wid  = tid >> 6;     // 0..7
  const int g    = lane >> 3;    // candidate slot within batch (0..7)
  const int e    = lane & 7;     // 32-elem octant (0..7)
  const int r0   = blockIdx.x * 64;
  if (tid == 0) blksum = 0.0f;
  __syncthreads();

  const int lane4 = lane * 4;
  float lacc = 0.0f;             // per-lane loss accumulator (deferred reduce)

  // classify this wave's 8 rows (row = wid + rr*8)
  int ncs[8], k0s[8];
  #pragma unroll
  for (int rr = 0; rr < 8; ++rr) {
    int row = r0 + wid + rr * 8;
    ncs[rr] = gcnt[row];
    k0s[rr] = gcand[(size_t)row * CAP];
  }

  // ---- fast rows: batched independent loads (one latency window) ----
  f4_t evs[8], xvs[8];
  #pragma unroll
  for (int rr = 0; rr < 8; ++rr) {
    if (ncs[rr] == 1) {          // wave-uniform branch
      int row = r0 + wid + rr * 8;
      xvs[rr] = *(const f4_t*)(xin + (size_t)row * D + lane4);
      evs[rr] = *(const f4_t*)(emb + (size_t)k0s[rr] * D + lane4);
    }
  }
  #pragma unroll
  for (int rr = 0; rr < 8; ++rr) {
    if (ncs[rr] == 1) {
      int row = r0 + wid + rr * 8;
      f4_t xv = xvs[rr];
      xv[0] = clipf(xv[0]); xv[1] = clipf(xv[1]);
      xv[2] = clipf(xv[2]); xv[3] = clipf(xv[3]);
      f4_t ev = evs[rr];
      *(f4_t*)(out + (size_t)row * D + lane4) = ev;
      #pragma unroll
      for (int i = 0; i < 4; ++i) { float df = ev[i] - xv[i]; lacc += df * df; }
    }
  }

  // ---- slow rows: full exact rescore (unchanged semantics) ----
  for (int rr = 0; rr < 8; ++rr) {
    if (ncs[rr] != 1) {          // wave-uniform
      const int row = wid + rr * 8;
      f4_t xv = *(const f4_t*)(xin + (size_t)(r0 + row) * D + lane4);
      xv[0] = clipf(xv[0]); xv[1] = clipf(xv[1]);
      xv[2] = clipf(xv[2]); xv[3] = clipf(xv[3]);
      *(f4_t*)&xrow[wid][lane4] = xv;
      __builtin_amdgcn_wave_barrier();
      if (lane < 16) {   // numpy pairwise sum of x^2 (exact order)
        const int hf = lane >> 3, jj = lane & 7;
        const float* base = &xrow[wid][hf * 128 + jj];
        float v = base[0];
        float rs = v * v;
        #pragma unroll
        for (int m = 1; m < 16; ++m) { v = base[8 * m]; rs += v * v; }
        rpart[wid][lane] = rs;
      }
      __builtin_amdgcn_wave_barrier();
      float p[16];
      #pragma unroll
      for (int j = 0; j < 16; ++j) p[j] = rpart[wid][j];
      float h0 = ((p[0] + p[1]) + (p[2] + p[3])) + ((p[4] + p[5]) + (p[6] + p[7]));
      float h1 = ((p[8] + p[9]) + (p[10] + p[11])) + ((p[12] + p[13]) + (p[14] + p[15]));
      float sx = h0 + h1;

      // hoist this lane's x octant (32 floats)
      f4_t xo[8];
      #pragma unroll
      for (int u = 0; u < 8; ++u) xo[u] = *(const f4_t*)&xrow[wid][e * 32 + u * 4];

      const int nc = ncs[rr];
      const unsigned short* cl = gcand + (size_t)(r0 + row) * CAP;
      float bd = INFINITY; int bk = 0x7fffffff;
      for (int bi = 0; bi < (nc + 7) >> 3; ++bi) {
        int ci = bi * 8 + g;
        bool valid = ci < nc;
        int k = valid ? cl[ci] : 0;
        const float* ep = emb + (size_t)k * D + e * 32;
        double dd = 0.0;
        #pragma unroll
        for (int u = 0; u < 8; ++u) {
          f4_t ev = *(const f4_t*)(ep + u * 4);
          dd += (double)xo[u][0] * (double)ev[0] + (double)xo[u][1] * (double)ev[1]
              + (double)xo[u][2] * (double)ev[2] + (double)xo[u][3] * (double)ev[3];
        }
        dd += __shfl_xor(dd, 1, 64);
        dd += __shfl_xor(dd, 2, 64);
        dd += __shfl_xor(dd, 4, 64);   // all 8 lanes of the group hold the full dot
        float T1 = sx + senp[k];       // fp32, numpy op order
        float T2 = (float)(2.0 * dd);
        float d  = valid ? (T1 - T2) : INFINITY;
        int   kk = valid ? k : 0x7fffffff;
        if (d < bd || (d == bd && kk < bk)) { bd = d; bk = kk; }
      }
      // cross-group lexicographic argmin (associative & commutative -> exact)
      #pragma unroll
      for (int off = 8; off < 64; off <<= 1) {
        float od = __shfl_xor(bd, off, 64);
        int   ok = __shfl_xor(bk, off, 64);
        if (od < bd || (od == bd && ok < bk)) { bd = od; bk = ok; }
      }

      f4_t ev = *(const f4_t*)(emb + (size_t)bk * D + lane4);
      *(f4_t*)(out + (size_t)(r0 + row) * D + lane4) = ev;
      #pragma unroll
      for (int i = 0; i < 4; ++i) { float df = ev[i] - xv[i]; lacc += df * df; }
    }
  }

  // one reduce per wave, one LDS atomic per wave, one global atomic per block
  #pragma unroll
  for (int off = 1; off < 64; off <<= 1) lacc += __shfl_xor(lacc, off, 64);
  if (lane == 0) atomicAdd(&blksum, lacc);
  __syncthreads();
  if (tid == 0) atomicAdd(lossacc, blksum);
}

// ---------------- finalize loss ----------------
__global__ void vq_fin(const float* __restrict__ lossacc, float* __restrict__ out) {
  out[NOUT] = 1.25f * lossacc[0] / 8388608.0f;
}

extern "C" void kernel_launch(void* const* d_in, const int* in_sizes, int n_in,
                              void* d_out, int out_size, void* d_ws, size_t ws_size,
                              hipStream_t stream) {
  const float* xin = (const float*)d_in[0];
  const float* emb = (const float*)d_in[1];
  float* out = (float*)d_out;
  _Float16* femb = (_Float16*)d_ws;                 // 4 MB (512 chunks x 8 KB)
  float* F       = (float*)d_ws + 1048576;
  float* senp    = F;                               // 8192
  float* ekkb    = F + 8192;                        // 8192
  float* lossacc = F + 16384;                       // 1
  int*   gcnt    = (int*)(F + 16640);               // 32768 ints
  unsigned short* gcand = (unsigned short*)(F + 16640 + 32768);  // 32768*32 u16
  vq_packsetup<<<dim3(1024), dim3(256), 0, stream>>>(emb, femb, senp, ekkb, lossacc);
  vq_score<<<dim3(NROWS / MB), dim3(THREADS), 0, stream>>>(xin, femb, ekkb, gcnt, gcand);
  vq_rescore<<<dim3(NROWS / 64), dim3(512), 0, stream>>>(xin, emb, senp, gcnt, gcand, out, lossacc);
  vq_fin<<<dim3(1), dim3(1), 0, stream>>>(lossacc, out);
}